// Round 6
// baseline (906.885 us; speedup 1.0000x reference)
//
#include <hip/hip_runtime.h>
#include <hip/hip_cooperative_groups.h>
#include <cstdint>

namespace cg = cooperative_groups;

#define TPB 256
#define GRID 512
typedef __attribute__((ext_vector_type(4))) float f4;

// ---------------------------------------------------------------------------
// Workspace layout (floats) — identical to round-3 best:
//   Y     @   512 (512)    C1IN = [Y|Z] @ 512 (1560)
//   Z     @  1024 (1048)
//   C1H   @  2072 (1600)
//   OUT12 @  3672 (4096)   [out1 | out2]
//   A1H   @  7768 (4096)
//   C2H   @ 11864 (4096)
//   OUT34 @ 15960 (8192)   [out3 | out4]
//   A2H   @ 24152 (4096)
//   NTH   @ 28248 (8192)
//   OUT6  @ 36440 (14336)  [out5 | out3copy | out1copy]
//   M2H   @ 50776 (8192)
//   HBUF  @ 58968 (8192)
//   M3H1  @ 67160 (512)
//   M3H2  @ 67672 (256)
//   end   @ 67928
// Zero range (atomic-accumulated buffers): [2072, 67928)
// ---------------------------------------------------------------------------

struct Desc {
    const float* x; const float* W; float* out; const float* bias;
    const int* nb;
    int in_dim, out_dim, chunk, ntile, nchunk, xs, os;
    int op;        // 0 direct, 1 relu-in, 2 agg, 3 maxpool8, 4 copy
    int aggdim;
    int nblocks;
};

struct Args {
    const float *center, *corner, *normal; const int* nbr;
    const float *spW1, *spb1, *spW2, *spb2;
    const float *Wc, *bc, *W3, *b3, *W4, *b4, *kck;
    const float *stW1, *stb1, *stW2, *stb2;
    const float *m3W3, *m3b3;
    float *ws; float *out;
    Desc d[16];
    int pend[10];   // desc end index per phase
    int ptot[10];   // total block-items per phase
    int nphase;
};

__global__ __launch_bounds__(TPB) void net_kernel(Args a) {
    cg::grid_group g = cg::this_grid();
    int tid = threadIdx.x;
    int b = blockIdx.x;
    float* ws = a.ws;
    __shared__ float sx[512];

    // ---------------- phase 0: front end + zeroing ----------------
    if (b < 8) {
        // one face per block: FRC conv+mlp, kernel correlation, structural MLP
        int f = b;
        __shared__ float sc[9], sn[3], sm[32], shh[64], sf[131], sh2[131];
        if (tid < 9) sc[tid] = a.corner[f * 9 + tid];
        if (tid < 3) { sn[tid] = a.normal[f * 3 + tid]; sf[tid] = a.normal[f * 3 + tid]; }
        __syncthreads();
        if (tid < 32) {                       // conv over 3 corner pairs, mean
            float acc = 0.f;
            for (int p = 0; p < 3; ++p) {
                const float* aa = &sc[3 * p];
                const float* bb = &sc[3 * ((p + 1) % 3)];
                float d = a.bc[tid];
                for (int k = 0; k < 3; ++k)
                    d += aa[k] * a.Wc[tid * 6 + k] + bb[k] * a.Wc[tid * 6 + 3 + k];
                acc += d;
            }
            sm[tid] = acc * (1.f / 3.f);
        }
        __syncthreads();
        if (tid < 64) {                       // frc hidden (32 -> 64), relu
            float h = a.b3[tid];
            for (int o = 0; o < 32; ++o) h = fmaf(sm[o], a.W3[o * 64 + tid], h);
            shh[tid] = fmaxf(h, 0.f);
        }
        if (tid < 64) {                       // kernel correlation -> sf[3+tid]
            float s = 0.f;
            for (int l = 0; l < 4; ++l) {
                float dx = sn[0] - a.kck[(tid * 4 + l) * 3 + 0];
                float dy = sn[1] - a.kck[(tid * 4 + l) * 3 + 1];
                float dz = sn[2] - a.kck[(tid * 4 + l) * 3 + 2];
                s += expf(-(dx * dx + dy * dy + dz * dz));
            }
            sf[3 + tid] = s * (1.f / 32.f);
        }
        __syncthreads();
        if (tid < 64) {                       // frc out (64 -> 64) -> sf[67+tid]
            float v = a.b4[tid];
            for (int k = 0; k < 64; ++k) v = fmaf(shh[k], a.W4[k * 64 + tid], v);
            sf[67 + tid] = v;
        }
        __syncthreads();
        if (tid < 131) {                      // st hidden, relu
            float v = a.stb1[tid];
            for (int k = 0; k < 131; ++k) v = fmaf(sf[k], a.stW1[k * 131 + tid], v);
            sh2[tid] = fmaxf(v, 0.f);
        }
        __syncthreads();
        if (tid < 131) {                      // st out -> Z
            float v = a.stb2[tid];
            for (int k = 0; k < 131; ++k) v = fmaf(sh2[k], a.stW2[k * 131 + tid], v);
            ws[1024 + f * 131 + tid] = v;
        }
    } else if (b < 12) {
        // spatial chain: T1 = relu(center@spW1+b1) in LDS; y = T1@spW2+b2
        int bs = b - 8;
        __shared__ float sctr[24], st1[512];
        if (tid < 24) sctr[tid] = a.center[tid];
        __syncthreads();
        for (int j = tid; j < 512; j += TPB) {
            float v = a.spb1[j];
            for (int i = 0; i < 24; ++i) v = fmaf(sctr[i], a.spW1[i * 512 + j], v);
            st1[j] = fmaxf(v, 0.f);
        }
        __syncthreads();
        if (tid < 128) {
            int j = bs * 128 + tid;
            float v = a.spb2[j];
            for (int k = 0; k < 512; ++k) v = fmaf(st1[k], a.spW2[k * 512 + j], v);
            ws[512 + j] = v;                  // Y, direct write
        }
    } else {
        // zero the atomic-accumulated region [2072, 67928)
        int zb = b - 12;
        f4 z4 = {0.f, 0.f, 0.f, 0.f};
        f4* p = (f4*)(ws + 2072);
        int n4 = (67928 - 2072) / 4;
        for (int i = zb * TPB + tid; i < n4; i += (GRID - 12) * TPB) p[i] = z4;
    }
    g.sync();

    // ---------------- phases 1..nphase: persistent multi-GEMV ----------------
    int dbeg = 0;
    for (int ph = 0; ph < a.nphase; ++ph) {
        int dend = a.pend[ph];
        int tot  = a.ptot[ph];
        for (int item = b; item < tot; item += GRID) {
            int di = dbeg, rb = item;
            while (di + 1 < dend && rb >= a.d[di].nblocks) { rb -= a.d[di].nblocks; ++di; }
            Desc d = a.d[di];
            if (d.op == 4) {                  // copy
                int i = rb * TPB + tid;
                int n4 = d.in_dim >> 2;
                if (i < n4) ((f4*)d.out)[i] = ((const f4*)d.x)[i];
                continue;
            }
            int per = d.ntile * d.nchunk;
            int vec = rb / per;
            int r = rb - vec * per;
            int ci = r / d.ntile;
            int tile = r - ci * d.ntile;
            const float* x = d.x + (size_t)vec * d.xs;
            float* out = d.out + (size_t)vec * d.os;
            int row0 = ci * d.chunk;
            int rows = min(d.chunk, d.in_dim - row0);
            __syncthreads();                  // protect sx from previous item readers
            for (int t = tid; t < rows; t += TPB) {
                int idx = row0 + t;
                float v;
                if (d.op == 2) {
                    int i = idx / d.aggdim, k = idx - i * d.aggdim;
                    const int* nb = d.nb + i * 3;
                    v = 0.25f * (x[i * d.aggdim + k] + x[nb[0] * d.aggdim + k] +
                                 x[nb[1] * d.aggdim + k] + x[nb[2] * d.aggdim + k]);
                } else if (d.op == 3) {
                    v = x[idx];
#pragma unroll
                    for (int f = 1; f < 8; ++f) v = fmaxf(v, x[f * d.in_dim + idx]);
                } else {
                    v = x[idx];
                    if (d.op == 1) v = fmaxf(v, 0.f);
                }
                sx[t] = v;
            }
            __syncthreads();
            int j = tile * (TPB * 4) + tid * 4;
            if (j >= d.out_dim) continue;
            const float* wp = d.W + (size_t)row0 * d.out_dim + j;
            float ax = 0.f, ay = 0.f, az = 0.f, aw = 0.f;
#pragma unroll 16
            for (int t = 0; t < rows; ++t) {
                f4 w = *(const f4*)wp;
                float xv = sx[t];
                ax = fmaf(xv, w[0], ax); ay = fmaf(xv, w[1], ay);
                az = fmaf(xv, w[2], az); aw = fmaf(xv, w[3], aw);
                wp += d.out_dim;
            }
            if (ci == 0 && d.bias) {
                ax += d.bias[j]; ay += d.bias[j + 1];
                az += d.bias[j + 2]; aw += d.bias[j + 3];
            }
            unsafeAtomicAdd(&out[j + 0], ax);
            unsafeAtomicAdd(&out[j + 1], ay);
            unsafeAtomicAdd(&out[j + 2], az);
            unsafeAtomicAdd(&out[j + 3], aw);
        }
        g.sync();
        dbeg = dend;
    }

    // ---------------- head: logits = relu(M3H2) @ m3_W3 + b3 ----------------
    if (b == 0) {
        const float* x = ws + 67672;          // M3H2
        if (tid < 256) sx[tid] = fmaxf(x[tid], 0.f);
        __syncthreads();
        if (tid < 40) {
            float v = a.m3b3[tid];
            for (int k = 0; k < 256; ++k) v = fmaf(sx[k], a.m3W3[k * 40 + tid], v);
            a.out[tid] = v;
        }
    }
}

// ---------------------------------------------------------------------------
static Desc tile_desc(const float* x, const float* W, float* out, const float* bias,
                      int in, int outd, int chunk, int op,
                      int nvec = 1, int xs = 0, int os = 0,
                      const int* nb = nullptr, int aggdim = 0) {
    Desc d{};
    d.x = x; d.W = W; d.out = out; d.bias = bias; d.nb = nb;
    d.in_dim = in; d.out_dim = outd; d.chunk = chunk;
    d.ntile = (outd + TPB * 4 - 1) / (TPB * 4);
    d.nchunk = (in + chunk - 1) / chunk;
    d.xs = xs; d.os = os;
    d.op = op; d.aggdim = aggdim;
    d.nblocks = d.ntile * d.nchunk * nvec;
    return d;
}
static Desc copy_desc(const float* src, float* dst, int n) {
    Desc d{};
    d.x = src; d.out = dst; d.in_dim = n; d.op = 4;
    d.nblocks = (n / 4 + TPB - 1) / TPB;
    return d;
}

extern "C" void kernel_launch(void* const* d_in, const int* in_sizes, int n_in,
                              void* d_out, int out_size, void* d_ws, size_t ws_size,
                              hipStream_t stream) {
    const float* center    = (const float*)d_in[0];
    const float* corner    = (const float*)d_in[1];
    const float* normal    = (const float*)d_in[2];
    const int*   neighbour = (const int*)  d_in[3];
    const float* sp_W1 = (const float*)d_in[4];
    const float* sp_b1 = (const float*)d_in[5];
    const float* sp_W2 = (const float*)d_in[6];
    const float* sp_b2 = (const float*)d_in[7];
    const float* frc_Wc = (const float*)d_in[8];
    const float* frc_bc = (const float*)d_in[9];
    const float* frc_W3 = (const float*)d_in[10];
    const float* frc_b3 = (const float*)d_in[11];
    const float* frc_W4 = (const float*)d_in[12];
    const float* frc_b4 = (const float*)d_in[13];
    const float* kc_kernel = (const float*)d_in[14];
    const float* st_W1 = (const float*)d_in[15];
    const float* st_b1 = (const float*)d_in[16];
    const float* st_W2 = (const float*)d_in[17];
    const float* st_b2 = (const float*)d_in[18];
    const float* c1_W1 = (const float*)d_in[19];
    const float* c1_b1 = (const float*)d_in[20];
    const float* c1_W2 = (const float*)d_in[21];
    const float* c1_b2 = (const float*)d_in[22];
    const float* a1_W3 = (const float*)d_in[23];
    const float* a1_b3 = (const float*)d_in[24];
    const float* a1_W4 = (const float*)d_in[25];
    const float* a1_b4 = (const float*)d_in[26];
    const float* c2_W1 = (const float*)d_in[27];
    const float* c2_b1 = (const float*)d_in[28];
    const float* c2_W2 = (const float*)d_in[29];
    const float* c2_b2 = (const float*)d_in[30];
    const float* a2_W3 = (const float*)d_in[31];
    const float* a2_b3 = (const float*)d_in[32];
    const float* a2_W4 = (const float*)d_in[33];
    const float* a2_b4 = (const float*)d_in[34];
    const float* nt_W1 = (const float*)d_in[35];
    const float* nt_b1 = (const float*)d_in[36];
    const float* nt_W2 = (const float*)d_in[37];
    const float* nt_b2 = (const float*)d_in[38];
    const float* m2_W1 = (const float*)d_in[39];
    const float* m2_b1 = (const float*)d_in[40];
    const float* m2_W2 = (const float*)d_in[41];
    const float* m2_b2 = (const float*)d_in[42];
    const float* m3_W1 = (const float*)d_in[43];
    const float* m3_b1 = (const float*)d_in[44];
    const float* m3_W2 = (const float*)d_in[45];
    const float* m3_b2 = (const float*)d_in[46];
    const float* m3_W3 = (const float*)d_in[47];
    const float* m3_b3 = (const float*)d_in[48];

    float* ws = (float*)d_ws;
    float* C1IN  = ws + 512;           // [Y(512) | Z(1048)]
    float* Z     = ws + 1024;
    float* C1H   = ws + 2072;
    float* OUT12 = ws + 3672;          // [out1 | out2]
    float* A1H   = ws + 7768;
    float* C2H   = ws + 11864;
    float* OUT34 = ws + 15960;         // [out3 | out4]
    float* A2H   = ws + 24152;
    float* NTH   = ws + 28248;
    float* OUT6  = ws + 36440;         // [out5 | out3c | out1c]
    float* M2H   = ws + 50776;
    float* HBUF  = ws + 58968;
    float* M3H1  = ws + 67160;
    float* M3H2  = ws + 67672;

    Args a{};
    a.center = center; a.corner = corner; a.normal = normal; a.nbr = neighbour;
    a.spW1 = sp_W1; a.spb1 = sp_b1; a.spW2 = sp_W2; a.spb2 = sp_b2;
    a.Wc = frc_Wc; a.bc = frc_bc; a.W3 = frc_W3; a.b3 = frc_b3;
    a.W4 = frc_W4; a.b4 = frc_b4; a.kck = kc_kernel;
    a.stW1 = st_W1; a.stb1 = st_b1; a.stW2 = st_W2; a.stb2 = st_b2;
    a.m3W3 = m3_W3; a.m3b3 = m3_b3;
    a.ws = ws; a.out = (float*)d_out;

    int k = 0, ph = 0, tot = 0;
    auto add = [&](Desc d) { a.d[k++] = d; tot += d.nblocks; };
    auto endp = [&]() { a.pend[ph] = k; a.ptot[ph] = tot; ++ph; tot = 0; };

    // ph1: a1_W3 (agg1 from Z) + c1_W1 (x=[y|z])
    add(tile_desc(Z, a1_W3, A1H, a1_b3, 1048, 4096, 16, 2, 1, 0, 0, neighbour, 131));
    add(tile_desc(C1IN, c1_W1, C1H, c1_b1, 1560, 1600, 26, 0));
    endp();
    // ph2: a1_W4 + c1_W2 -> OUT12
    add(tile_desc(A1H, a1_W4, OUT12 + 2048, a1_b4, 4096, 2048, 32, 1));
    add(tile_desc(C1H, c1_W2, OUT12, c1_b2, 1600, 2048, 16, 1));
    endp();
    // ph3: c2_W1 + a2_W3 (agg2 from out2)
    add(tile_desc(OUT12, c2_W1, C2H, c2_b1, 4096, 4096, 64, 0));
    add(tile_desc(OUT12 + 2048, a2_W3, A2H, a2_b3, 2048, 4096, 32, 2, 1, 0, 0, neighbour, 256));
    endp();
    // ph4: c2_W2 + a2_W4 -> OUT34 + copy out1 -> OUT6 tail
    add(tile_desc(C2H, c2_W2, OUT34, c2_b2, 4096, 4096, 64, 1));
    add(tile_desc(A2H, a2_W4, OUT34 + 4096, a2_b4, 4096, 4096, 64, 1));
    add(copy_desc(OUT12, OUT6 + 12288, 2048));
    endp();
    // ph5: nt_W1 (8 faces) + copy out3 -> OUT6 mid
    add(tile_desc(OUT34, nt_W1, NTH, nt_b1, 1024, 1024, 32, 0, 8, 1024, 1024));
    add(copy_desc(OUT34, OUT6 + 8192, 4096));
    endp();
    // ph6: nt_W2 -> out5
    add(tile_desc(NTH, nt_W2, OUT6, nt_b2, 1024, 1024, 32, 1, 8, 1024, 1024));
    endp();
    // ph7: m2_W1
    add(tile_desc(OUT6, m2_W1, M2H, m2_b1, 14336, 8192, 112, 0));
    endp();
    // ph8: m2_W2
    add(tile_desc(M2H, m2_W2, HBUF, m2_b2, 8192, 8192, 64, 1));
    endp();
    // ph9: m3_W1 with inline maxpool
    add(tile_desc(HBUF, m3_W1, M3H1, m3_b1, 1024, 512, 8, 3));
    endp();
    // ph10: m3_W2
    add(tile_desc(M3H1, m3_W2, M3H2, m3_b2, 512, 256, 8, 1));
    endp();
    a.nphase = ph;

    void* kp[] = { &a };
    hipLaunchCooperativeKernel((void*)net_kernel, dim3(GRID), dim3(TPB), kp, 0, stream);
}

// Round 7
// 514.230 us; speedup vs baseline: 1.7636x; 1.7636x over previous
//
#include <hip/hip_runtime.h>
#include <cstdint>

#define TPB 256
typedef __attribute__((ext_vector_type(4))) float f4;

// ---------------------------------------------------------------------------
// Workspace layout (floats):
//   Y     @   512 (512)    C1IN = [Y|Z] @ 512 (1560)
//   Z     @  1024 (1048)
//   C1H   @  2072 (1600)
//   OUT12 @  3672 (4096)   [out1 | out2]
//   A1H   @  7768 (4096)
//   C2H   @ 11864 (4096)
//   OUT34 @ 15960 (8192)   [out3 | out4]
//   A2H   @ 24152 (4096)
//   NTH   @ 28248 (8192)
//   OUT6  @ 36440 (14336)  [out5 | out3copy | out1copy]
//   M2H   @ 50776 (8192)
//   HBUF  @ 58968 (8192)
//   M3H1  @ 67160 (512)
//   M3H2  @ 67672 (256)
//   end   @ 67928
// Zero range (atomic-accumulated buffers): [2072, 67928)
// ---------------------------------------------------------------------------

__global__ __launch_bounds__(TPB) void stage1_kernel(
    const float* __restrict__ center, const float* __restrict__ corner,
    const float* __restrict__ normal,
    const float* __restrict__ spW1, const float* __restrict__ spb1,
    const float* __restrict__ spW2, const float* __restrict__ spb2,
    const float* __restrict__ Wc, const float* __restrict__ bc,
    const float* __restrict__ W3, const float* __restrict__ b3,
    const float* __restrict__ W4, const float* __restrict__ b4,
    const float* __restrict__ kck,
    const float* __restrict__ stW1, const float* __restrict__ stb1,
    const float* __restrict__ stW2, const float* __restrict__ stb2,
    float* __restrict__ ws) {
    int tid = threadIdx.x;
    int b = blockIdx.x;
    if (b < 8) {
        // ---- one face per block: FRC conv+mlp, kernel correlation, st MLP
        int f = b;
        __shared__ float sc[9], sn[3], sm[32], shh[64], sf[131], sh2[131];
        if (tid < 9) sc[tid] = corner[f * 9 + tid];
        if (tid < 3) { sn[tid] = normal[f * 3 + tid]; sf[tid] = normal[f * 3 + tid]; }
        __syncthreads();
        if (tid < 32) {                       // conv over 3 corner pairs, mean
            float acc = 0.f;
            for (int p = 0; p < 3; ++p) {
                const float* a  = &sc[3 * p];
                const float* b2 = &sc[3 * ((p + 1) % 3)];
                float d = bc[tid];
                for (int k = 0; k < 3; ++k)
                    d += a[k] * Wc[tid * 6 + k] + b2[k] * Wc[tid * 6 + 3 + k];
                acc += d;
            }
            sm[tid] = acc * (1.f / 3.f);
        }
        __syncthreads();
        if (tid < 64) {                       // frc hidden (32 -> 64), relu
            float h = b3[tid];
            for (int o = 0; o < 32; ++o) h = fmaf(sm[o], W3[o * 64 + tid], h);
            shh[tid] = fmaxf(h, 0.f);
        }
        if (tid < 64) {                       // kernel correlation -> sf[3+tid]
            float s = 0.f;
            for (int l = 0; l < 4; ++l) {
                float dx = sn[0] - kck[(tid * 4 + l) * 3 + 0];
                float dy = sn[1] - kck[(tid * 4 + l) * 3 + 1];
                float dz = sn[2] - kck[(tid * 4 + l) * 3 + 2];
                s += expf(-(dx * dx + dy * dy + dz * dz));
            }
            sf[3 + tid] = s * (1.f / 32.f);
        }
        __syncthreads();
        if (tid < 64) {                       // frc out (64 -> 64) -> sf[67+tid]
            float v = b4[tid];
            for (int k = 0; k < 64; ++k) v = fmaf(shh[k], W4[k * 64 + tid], v);
            sf[67 + tid] = v;
        }
        __syncthreads();
        if (tid < 131) {                      // st hidden, relu
            float a = stb1[tid];
            for (int k = 0; k < 131; ++k) a = fmaf(sf[k], stW1[k * 131 + tid], a);
            sh2[tid] = fmaxf(a, 0.f);
        }
        __syncthreads();
        if (tid < 131) {                      // st out -> Z
            float a = stb2[tid];
            for (int k = 0; k < 131; ++k) a = fmaf(sh2[k], stW2[k * 131 + tid], a);
            ws[1024 + f * 131 + tid] = a;
        }
    } else if (b < 12) {
        // ---- spatial chain: T1 = relu(center@spW1+b1) in LDS; y = T1@spW2+b2
        int bs = b - 8;
        __shared__ float sctr[24], st1[512];
        if (tid < 24) sctr[tid] = center[tid];
        __syncthreads();
        for (int j = tid; j < 512; j += TPB) {
            float a = spb1[j];
            for (int i = 0; i < 24; ++i) a = fmaf(sctr[i], spW1[i * 512 + j], a);
            st1[j] = fmaxf(a, 0.f);
        }
        __syncthreads();
        if (tid < 128) {
            int j = bs * 128 + tid;
            float a = spb2[j];
            for (int k = 0; k < 512; ++k) a = fmaf(st1[k], spW2[k * 512 + j], a);
            ws[512 + j] = a;                  // Y, direct write
        }
    } else {
        // ---- zero the atomic-accumulated region [2072, 67928)
        int zb = b - 12;                      // 0..31
        f4 z4 = {0.f, 0.f, 0.f, 0.f};
        f4* p = (f4*)(ws + 2072);
        int n4 = (67928 - 2072) / 4;          // 16464
        for (int i = zb * TPB + tid; i < n4; i += 32 * TPB) p[i] = z4;
    }
}

// ---------------------------------------------------------------------------
// Multi-GEMV: up to 3 descriptors per launch. Split-K with HW f32 atomics
// onto zeroed buffers; bias folded into the ci==0 chunk; x-staging fuses
// relu / neighbour-agg / maxpool; op 4 = plain float4 copy.
// pan=2: each thread owns cols j and j+1024 (two independent 16B loads/row,
// doubled ILP, halved ntile) — used for large out_dim layers.
// ---------------------------------------------------------------------------
struct Desc {
    const float* x; const float* W; float* out; const float* bias;
    const int* nb;
    int in_dim, out_dim, chunk, ntile, nchunk, nvec, xs, os;
    int op;        // 0 direct, 1 relu-in, 2 agg, 3 maxpool8, 4 copy
    int aggdim;
    int pan;       // 1 or 2 column panels per block
    int nblocks;
};
struct Descs { Desc d[3]; int nd; };

__global__ __launch_bounds__(TPB) void mg_kernel(Descs D) {
    int bid = blockIdx.x;
    int di = 0;
    while (di + 1 < D.nd && bid >= D.d[di].nblocks) { bid -= D.d[di].nblocks; ++di; }
    Desc d = D.d[di];
    int tid = threadIdx.x;
    if (d.op == 4) {                          // copy
        int i = bid * TPB + tid;
        int n4 = d.in_dim >> 2;
        if (i < n4) ((f4*)d.out)[i] = ((const f4*)d.x)[i];
        return;
    }
    __shared__ float sx[64];
    int per = d.ntile * d.nchunk;
    int vec = bid / per;
    int r = bid - vec * per;
    int ci = r / d.ntile;
    int tile = r - ci * d.ntile;
    const float* x = d.x + (size_t)vec * d.xs;
    float* out = d.out + (size_t)vec * d.os;
    int row0 = ci * d.chunk;
    int rows = min(d.chunk, d.in_dim - row0);
    for (int t = tid; t < rows; t += TPB) {
        int idx = row0 + t;
        float v;
        if (d.op == 2) {
            int i = idx / d.aggdim, k = idx - i * d.aggdim;
            const int* nb = d.nb + i * 3;
            v = 0.25f * (x[i * d.aggdim + k] + x[nb[0] * d.aggdim + k] +
                         x[nb[1] * d.aggdim + k] + x[nb[2] * d.aggdim + k]);
        } else if (d.op == 3) {
            v = x[idx];
#pragma unroll
            for (int f = 1; f < 8; ++f) v = fmaxf(v, x[f * d.in_dim + idx]);
        } else {
            v = x[idx];
            if (d.op == 1) v = fmaxf(v, 0.f);
        }
        sx[t] = v;
    }
    __syncthreads();

    if (d.pan == 2) {
        int j = tile * 2048 + tid * 4;        // cols j and j+1024 (out_dim % 2048 == 0)
        const float* wp = d.W + (size_t)row0 * d.out_dim + j;
        float ax = 0.f, ay = 0.f, az = 0.f, aw = 0.f;
        float bx = 0.f, by = 0.f, bz = 0.f, bw = 0.f;
#pragma unroll 8
        for (int t = 0; t < rows; ++t) {
            f4 w0 = *(const f4*)wp;
            f4 w1 = *(const f4*)(wp + 1024);
            float xv = sx[t];
            ax = fmaf(xv, w0[0], ax); ay = fmaf(xv, w0[1], ay);
            az = fmaf(xv, w0[2], az); aw = fmaf(xv, w0[3], aw);
            bx = fmaf(xv, w1[0], bx); by = fmaf(xv, w1[1], by);
            bz = fmaf(xv, w1[2], bz); bw = fmaf(xv, w1[3], bw);
            wp += d.out_dim;
        }
        if (ci == 0 && d.bias) {
            ax += d.bias[j];        ay += d.bias[j + 1];
            az += d.bias[j + 2];    aw += d.bias[j + 3];
            bx += d.bias[j + 1024]; by += d.bias[j + 1025];
            bz += d.bias[j + 1026]; bw += d.bias[j + 1027];
        }
        unsafeAtomicAdd(&out[j + 0], ax);
        unsafeAtomicAdd(&out[j + 1], ay);
        unsafeAtomicAdd(&out[j + 2], az);
        unsafeAtomicAdd(&out[j + 3], aw);
        unsafeAtomicAdd(&out[j + 1024], bx);
        unsafeAtomicAdd(&out[j + 1025], by);
        unsafeAtomicAdd(&out[j + 1026], bz);
        unsafeAtomicAdd(&out[j + 1027], bw);
        return;
    }

    int j = tile * (TPB * 4) + tid * 4;
    if (j >= d.out_dim) return;
    const float* wp = d.W + (size_t)row0 * d.out_dim + j;
    float ax = 0.f, ay = 0.f, az = 0.f, aw = 0.f;
#pragma unroll 16
    for (int t = 0; t < rows; ++t) {
        f4 w = *(const f4*)wp;
        float xv = sx[t];
        ax = fmaf(xv, w[0], ax); ay = fmaf(xv, w[1], ay);
        az = fmaf(xv, w[2], az); aw = fmaf(xv, w[3], aw);
        wp += d.out_dim;
    }
    if (ci == 0 && d.bias) {
        ax += d.bias[j]; ay += d.bias[j + 1]; az += d.bias[j + 2]; aw += d.bias[j + 3];
    }
    unsafeAtomicAdd(&out[j + 0], ax);
    unsafeAtomicAdd(&out[j + 1], ay);
    unsafeAtomicAdd(&out[j + 2], az);
    unsafeAtomicAdd(&out[j + 3], aw);
}

// head: logits = relu(M3H2) @ m3_W3 + b3   (256 -> 40)
__global__ __launch_bounds__(64) void head_kernel(
    const float* __restrict__ x, const float* __restrict__ W,
    const float* __restrict__ b, float* __restrict__ out) {
    __shared__ float sx[256];
    int tid = threadIdx.x;
    for (int k = tid; k < 256; k += 64) sx[k] = fmaxf(x[k], 0.f);
    __syncthreads();
    if (tid < 40) {
        float a = b[tid];
        for (int k = 0; k < 256; ++k) a = fmaf(sx[k], W[k * 40 + tid], a);
        out[tid] = a;
    }
}

// ---------------------------------------------------------------------------
static Desc gemv_desc(const float* x, const float* W, float* out, const float* bias,
                      int in, int outd, int chunk, int op, int pan,
                      int nvec = 1, int xs = 0, int os = 0,
                      const int* nb = nullptr, int aggdim = 0) {
    Desc d{};
    d.x = x; d.W = W; d.out = out; d.bias = bias; d.nb = nb;
    d.in_dim = in; d.out_dim = outd; d.chunk = chunk;
    int width = pan * 1024;
    d.ntile = (outd + width - 1) / width;
    d.nchunk = (in + chunk - 1) / chunk;
    d.nvec = nvec; d.xs = xs; d.os = os;
    d.op = op; d.aggdim = aggdim; d.pan = pan;
    d.nblocks = d.ntile * d.nchunk * nvec;
    return d;
}
static Desc copy_desc(const float* src, float* dst, int n) {
    Desc d{};
    d.x = src; d.out = dst; d.in_dim = n; d.op = 4; d.pan = 1;
    d.nblocks = (n / 4 + TPB - 1) / TPB;
    return d;
}
static void mg1(hipStream_t s, Desc a) {
    Descs D{}; D.d[0] = a; D.nd = 1;
    mg_kernel<<<a.nblocks, TPB, 0, s>>>(D);
}
static void mg2(hipStream_t s, Desc a, Desc b) {
    Descs D{}; D.d[0] = a; D.d[1] = b; D.nd = 2;
    mg_kernel<<<a.nblocks + b.nblocks, TPB, 0, s>>>(D);
}
static void mg3(hipStream_t s, Desc a, Desc b, Desc c) {
    Descs D{}; D.d[0] = a; D.d[1] = b; D.d[2] = c; D.nd = 3;
    mg_kernel<<<a.nblocks + b.nblocks + c.nblocks, TPB, 0, s>>>(D);
}

extern "C" void kernel_launch(void* const* d_in, const int* in_sizes, int n_in,
                              void* d_out, int out_size, void* d_ws, size_t ws_size,
                              hipStream_t stream) {
    const float* center    = (const float*)d_in[0];
    const float* corner    = (const float*)d_in[1];
    const float* normal    = (const float*)d_in[2];
    const int*   neighbour = (const int*)  d_in[3];
    const float* sp_W1 = (const float*)d_in[4];
    const float* sp_b1 = (const float*)d_in[5];
    const float* sp_W2 = (const float*)d_in[6];
    const float* sp_b2 = (const float*)d_in[7];
    const float* frc_Wc = (const float*)d_in[8];
    const float* frc_bc = (const float*)d_in[9];
    const float* frc_W3 = (const float*)d_in[10];
    const float* frc_b3 = (const float*)d_in[11];
    const float* frc_W4 = (const float*)d_in[12];
    const float* frc_b4 = (const float*)d_in[13];
    const float* kc_kernel = (const float*)d_in[14];
    const float* st_W1 = (const float*)d_in[15];
    const float* st_b1 = (const float*)d_in[16];
    const float* st_W2 = (const float*)d_in[17];
    const float* st_b2 = (const float*)d_in[18];
    const float* c1_W1 = (const float*)d_in[19];
    const float* c1_b1 = (const float*)d_in[20];
    const float* c1_W2 = (const float*)d_in[21];
    const float* c1_b2 = (const float*)d_in[22];
    const float* a1_W3 = (const float*)d_in[23];
    const float* a1_b3 = (const float*)d_in[24];
    const float* a1_W4 = (const float*)d_in[25];
    const float* a1_b4 = (const float*)d_in[26];
    const float* c2_W1 = (const float*)d_in[27];
    const float* c2_b1 = (const float*)d_in[28];
    const float* c2_W2 = (const float*)d_in[29];
    const float* c2_b2 = (const float*)d_in[30];
    const float* a2_W3 = (const float*)d_in[31];
    const float* a2_b3 = (const float*)d_in[32];
    const float* a2_W4 = (const float*)d_in[33];
    const float* a2_b4 = (const float*)d_in[34];
    const float* nt_W1 = (const float*)d_in[35];
    const float* nt_b1 = (const float*)d_in[36];
    const float* nt_W2 = (const float*)d_in[37];
    const float* nt_b2 = (const float*)d_in[38];
    const float* m2_W1 = (const float*)d_in[39];
    const float* m2_b1 = (const float*)d_in[40];
    const float* m2_W2 = (const float*)d_in[41];
    const float* m2_b2 = (const float*)d_in[42];
    const float* m3_W1 = (const float*)d_in[43];
    const float* m3_b1 = (const float*)d_in[44];
    const float* m3_W2 = (const float*)d_in[45];
    const float* m3_b2 = (const float*)d_in[46];
    const float* m3_W3 = (const float*)d_in[47];
    const float* m3_b3 = (const float*)d_in[48];

    float* ws = (float*)d_ws;
    float* C1IN  = ws + 512;           // [Y(512) | Z(1048)]
    float* Z     = ws + 1024;
    float* C1H   = ws + 2072;
    float* OUT12 = ws + 3672;          // [out1 | out2]
    float* A1H   = ws + 7768;
    float* C2H   = ws + 11864;
    float* OUT34 = ws + 15960;         // [out3 | out4]
    float* A2H   = ws + 24152;
    float* NTH   = ws + 28248;
    float* OUT6  = ws + 36440;         // [out5 | out3c | out1c]
    float* M2H   = ws + 50776;
    float* HBUF  = ws + 58968;
    float* M3H1  = ws + 67160;
    float* M3H2  = ws + 67672;

    // L1: faces + spatial chain + zeroing
    stage1_kernel<<<44, TPB, 0, stream>>>(center, corner, normal,
        sp_W1, sp_b1, sp_W2, sp_b2, frc_Wc, frc_bc, frc_W3, frc_b3,
        frc_W4, frc_b4, kc_kernel, st_W1, st_b1, st_W2, st_b2, ws);

    // L2: a1_W3 (agg1 from Z) + c1_W1 (x=[y|z])
    mg2(stream,
        gemv_desc(Z, a1_W3, A1H, a1_b3, 1048, 4096, 16, 2, 1, 1, 0, 0, neighbour, 131),
        gemv_desc(C1IN, c1_W1, C1H, c1_b1, 1560, 1600, 26, 0, 1));
    // L3: a1_W4 + c1_W2 -> OUT12 = [out1 | out2]
    mg2(stream,
        gemv_desc(A1H, a1_W4, OUT12 + 2048, a1_b4, 4096, 2048, 16, 1, 2),
        gemv_desc(C1H, c1_W2, OUT12, c1_b2, 1600, 2048, 8, 1, 2));
    // L4: c2_W1 + a2_W3 (agg2 inline from out2)
    mg2(stream,
        gemv_desc(OUT12, c2_W1, C2H, c2_b1, 4096, 4096, 16, 0, 2),
        gemv_desc(OUT12 + 2048, a2_W3, A2H, a2_b3, 2048, 4096, 8, 2, 2, 1, 0, 0, neighbour, 256));
    // L5: c2_W2 + a2_W4 -> OUT34 + copy out1 -> OUT6 tail
    mg3(stream,
        gemv_desc(C2H, c2_W2, OUT34, c2_b2, 4096, 4096, 16, 1, 2),
        gemv_desc(A2H, a2_W4, OUT34 + 4096, a2_b4, 4096, 4096, 16, 1, 2),
        copy_desc(OUT12, OUT6 + 12288, 2048));
    // L6: nt_W1 (8 faces, L2-cached reuse) + copy out3 -> OUT6 mid
    mg2(stream,
        gemv_desc(OUT34, nt_W1, NTH, nt_b1, 1024, 1024, 16, 0, 1, 8, 1024, 1024),
        copy_desc(OUT34, OUT6 + 8192, 4096));
    // L7: nt_W2 -> out5
    mg1(stream,
        gemv_desc(NTH, nt_W2, OUT6, nt_b2, 1024, 1024, 16, 1, 1, 8, 1024, 1024));
    // L8: m2_W1 (470 MB)
    mg1(stream, gemv_desc(OUT6, m2_W1, M2H, m2_b1, 14336, 8192, 56, 0, 2));
    // L9: m2_W2 (268 MB)
    mg1(stream, gemv_desc(M2H, m2_W2, HBUF, m2_b2, 8192, 8192, 32, 1, 2));
    // L10: m3_W1 with inline maxpool over 8 faces
    mg1(stream, gemv_desc(HBUF, m3_W1, M3H1, m3_b1, 1024, 512, 8, 3, 1));
    // L11: m3_W2
    mg1(stream, gemv_desc(M3H1, m3_W2, M3H2, m3_b2, 512, 256, 8, 1, 1));
    // L12: head
    head_kernel<<<1, 64, 0, stream>>>(M3H2, m3_W3, m3_b3, (float*)d_out);
}

// Round 8
// 394.713 us; speedup vs baseline: 2.2976x; 1.3028x over previous
//
#include <hip/hip_runtime.h>
#include <cstdint>

#define TPB 256
typedef __attribute__((ext_vector_type(4))) float f4;

// ---------------------------------------------------------------------------
// Workspace layout (floats):
//   Y     @   512 (512)    C1IN = [Y|Z] @ 512 (1560)
//   Z     @  1024 (1048)
//   C1H   @  2072 (1600)
//   OUT12 @  3672 (4096)   [out1 | out2]
//   A1H   @  7768 (4096)
//   C2H   @ 11864 (4096)
//   OUT34 @ 15960 (8192)   [out3 | out4]
//   A2H   @ 24152 (4096)
//   NTH   @ 28248 (8192)
//   OUT6  @ 36440 (14336)  [out5 | out3copy | out1copy]
//   M2H   @ 50776 (8192)
//   HBUF  @ 58968 (8192)
//   M3H1  @ 67160 (512)
//   M3H2  @ 67672 (256)
//   end   @ 67928
// Zero range (atomic-accumulated buffers): [2072, 67928)
// ---------------------------------------------------------------------------

__global__ __launch_bounds__(TPB) void stage1_kernel(
    const float* __restrict__ center, const float* __restrict__ corner,
    const float* __restrict__ normal,
    const float* __restrict__ spW1, const float* __restrict__ spb1,
    const float* __restrict__ spW2, const float* __restrict__ spb2,
    const float* __restrict__ Wc, const float* __restrict__ bc,
    const float* __restrict__ W3, const float* __restrict__ b3,
    const float* __restrict__ W4, const float* __restrict__ b4,
    const float* __restrict__ kck,
    const float* __restrict__ stW1, const float* __restrict__ stb1,
    const float* __restrict__ stW2, const float* __restrict__ stb2,
    float* __restrict__ ws) {
    int tid = threadIdx.x;
    int b = blockIdx.x;
    if (b < 8) {
        // ---- one face per block: FRC conv+mlp, kernel correlation, st MLP
        int f = b;
        __shared__ float sc[9], sn[3], sm[32], shh[64], sf[131], sh2[131];
        if (tid < 9) sc[tid] = corner[f * 9 + tid];
        if (tid < 3) { sn[tid] = normal[f * 3 + tid]; sf[tid] = normal[f * 3 + tid]; }
        __syncthreads();
        if (tid < 32) {                       // conv over 3 corner pairs, mean
            float acc = 0.f;
            for (int p = 0; p < 3; ++p) {
                const float* a  = &sc[3 * p];
                const float* b2 = &sc[3 * ((p + 1) % 3)];
                float d = bc[tid];
                for (int k = 0; k < 3; ++k)
                    d += a[k] * Wc[tid * 6 + k] + b2[k] * Wc[tid * 6 + 3 + k];
                acc += d;
            }
            sm[tid] = acc * (1.f / 3.f);
        }
        __syncthreads();
        if (tid < 64) {                       // frc hidden (32 -> 64), relu
            float h = b3[tid];
            for (int o = 0; o < 32; ++o) h = fmaf(sm[o], W3[o * 64 + tid], h);
            shh[tid] = fmaxf(h, 0.f);
        }
        if (tid < 64) {                       // kernel correlation -> sf[3+tid]
            float s = 0.f;
            for (int l = 0; l < 4; ++l) {
                float dx = sn[0] - kck[(tid * 4 + l) * 3 + 0];
                float dy = sn[1] - kck[(tid * 4 + l) * 3 + 1];
                float dz = sn[2] - kck[(tid * 4 + l) * 3 + 2];
                s += expf(-(dx * dx + dy * dy + dz * dz));
            }
            sf[3 + tid] = s * (1.f / 32.f);
        }
        __syncthreads();
        if (tid < 64) {                       // frc out (64 -> 64) -> sf[67+tid]
            float v = b4[tid];
            for (int k = 0; k < 64; ++k) v = fmaf(shh[k], W4[k * 64 + tid], v);
            sf[67 + tid] = v;
        }
        __syncthreads();
        if (tid < 131) {                      // st hidden, relu
            float a = stb1[tid];
            for (int k = 0; k < 131; ++k) a = fmaf(sf[k], stW1[k * 131 + tid], a);
            sh2[tid] = fmaxf(a, 0.f);
        }
        __syncthreads();
        if (tid < 131) {                      // st out -> Z
            float a = stb2[tid];
            for (int k = 0; k < 131; ++k) a = fmaf(sh2[k], stW2[k * 131 + tid], a);
            ws[1024 + f * 131 + tid] = a;
        }
    } else if (b < 12) {
        // ---- spatial chain: T1 = relu(center@spW1+b1) in LDS; y = T1@spW2+b2
        int bs = b - 8;
        __shared__ float sctr[24], st1[512];
        if (tid < 24) sctr[tid] = center[tid];
        __syncthreads();
        for (int j = tid; j < 512; j += TPB) {
            float a = spb1[j];
            for (int i = 0; i < 24; ++i) a = fmaf(sctr[i], spW1[i * 512 + j], a);
            st1[j] = fmaxf(a, 0.f);
        }
        __syncthreads();
        if (tid < 128) {
            int j = bs * 128 + tid;
            float a = spb2[j];
            for (int k = 0; k < 512; ++k) a = fmaf(st1[k], spW2[k * 512 + j], a);
            ws[512 + j] = a;                  // Y, direct write
        }
    } else {
        // ---- zero the atomic-accumulated region [2072, 67928)
        int zb = b - 12;                      // 0..31
        f4 z4 = {0.f, 0.f, 0.f, 0.f};
        f4* p = (f4*)(ws + 2072);
        int n4 = (67928 - 2072) / 4;          // 16464
        for (int i = zb * TPB + tid; i < n4; i += 32 * TPB) p[i] = z4;
    }
}

// ---------------------------------------------------------------------------
// Multi-GEMV: up to 3 descriptors per launch. Split-K with HW f32 atomics
// onto zeroed buffers; bias folded into the ci==0 chunk; x-staging fuses
// relu / neighbour-agg / maxpool; op 4 = plain float4 copy.
// Grids shaped so every major stream gets 2-4 blocks/CU (occupancy lever).
// ---------------------------------------------------------------------------
struct Desc {
    const float* x; const float* W; float* out; const float* bias;
    const int* nb;
    int in_dim, out_dim, chunk, ntile, nchunk, nvec, xs, os;
    int op;        // 0 direct, 1 relu-in, 2 agg, 3 maxpool8, 4 copy
    int aggdim;
    int nblocks;
};
struct Descs { Desc d[3]; int nd; };

__global__ __launch_bounds__(TPB) void mg_kernel(Descs D) {
    int bid = blockIdx.x;
    int di = 0;
    while (di + 1 < D.nd && bid >= D.d[di].nblocks) { bid -= D.d[di].nblocks; ++di; }
    Desc d = D.d[di];
    int tid = threadIdx.x;
    if (d.op == 4) {                          // copy
        int i = bid * TPB + tid;
        int n4 = d.in_dim >> 2;
        if (i < n4) ((f4*)d.out)[i] = ((const f4*)d.x)[i];
        return;
    }
    __shared__ float sx[512];
    int per = d.ntile * d.nchunk;
    int vec = bid / per;
    int r = bid - vec * per;
    int ci = r / d.ntile;
    int tile = r - ci * d.ntile;
    const float* x = d.x + (size_t)vec * d.xs;
    float* out = d.out + (size_t)vec * d.os;
    int row0 = ci * d.chunk;
    int rows = min(d.chunk, d.in_dim - row0);
    for (int t = tid; t < rows; t += TPB) {
        int idx = row0 + t;
        float v;
        if (d.op == 2) {
            int i = idx / d.aggdim, k = idx - i * d.aggdim;
            const int* nb = d.nb + i * 3;
            v = 0.25f * (x[i * d.aggdim + k] + x[nb[0] * d.aggdim + k] +
                         x[nb[1] * d.aggdim + k] + x[nb[2] * d.aggdim + k]);
        } else if (d.op == 3) {
            v = x[idx];
#pragma unroll
            for (int f = 1; f < 8; ++f) v = fmaxf(v, x[f * d.in_dim + idx]);
        } else {
            v = x[idx];
            if (d.op == 1) v = fmaxf(v, 0.f);
        }
        sx[t] = v;
    }
    __syncthreads();
    int j = tile * (TPB * 4) + tid * 4;
    if (j >= d.out_dim) return;
    const float* wp = d.W + (size_t)row0 * d.out_dim + j;
    float ax = 0.f, ay = 0.f, az = 0.f, aw = 0.f;
#pragma unroll 16
    for (int t = 0; t < rows; ++t) {
        f4 w = *(const f4*)wp;
        float xv = sx[t];
        ax = fmaf(xv, w[0], ax); ay = fmaf(xv, w[1], ay);
        az = fmaf(xv, w[2], az); aw = fmaf(xv, w[3], aw);
        wp += d.out_dim;
    }
    if (ci == 0 && d.bias) {
        ax += d.bias[j]; ay += d.bias[j + 1]; az += d.bias[j + 2]; aw += d.bias[j + 3];
    }
    unsafeAtomicAdd(&out[j + 0], ax);
    unsafeAtomicAdd(&out[j + 1], ay);
    unsafeAtomicAdd(&out[j + 2], az);
    unsafeAtomicAdd(&out[j + 3], aw);
}

// head: logits = relu(M3H2) @ m3_W3 + b3   (256 -> 40)
__global__ __launch_bounds__(64) void head_kernel(
    const float* __restrict__ x, const float* __restrict__ W,
    const float* __restrict__ b, float* __restrict__ out) {
    __shared__ float sx[256];
    int tid = threadIdx.x;
    for (int k = tid; k < 256; k += 64) sx[k] = fmaxf(x[k], 0.f);
    __syncthreads();
    if (tid < 40) {
        float a = b[tid];
        for (int k = 0; k < 256; ++k) a = fmaf(sx[k], W[k * 40 + tid], a);
        out[tid] = a;
    }
}

// ---------------------------------------------------------------------------
static Desc gemv_desc(const float* x, const float* W, float* out, const float* bias,
                      int in, int outd, int chunk, int op,
                      int nvec = 1, int xs = 0, int os = 0,
                      const int* nb = nullptr, int aggdim = 0) {
    Desc d{};
    d.x = x; d.W = W; d.out = out; d.bias = bias; d.nb = nb;
    d.in_dim = in; d.out_dim = outd; d.chunk = chunk;
    d.ntile = (outd + TPB * 4 - 1) / (TPB * 4);
    d.nchunk = (in + chunk - 1) / chunk;
    d.nvec = nvec; d.xs = xs; d.os = os;
    d.op = op; d.aggdim = aggdim;
    d.nblocks = d.ntile * d.nchunk * nvec;
    return d;
}
static Desc copy_desc(const float* src, float* dst, int n) {
    Desc d{};
    d.x = src; d.out = dst; d.in_dim = n; d.op = 4;
    d.nblocks = (n / 4 + TPB - 1) / TPB;
    return d;
}
static void mg1(hipStream_t s, Desc a) {
    Descs D{}; D.d[0] = a; D.nd = 1;
    mg_kernel<<<a.nblocks, TPB, 0, s>>>(D);
}
static void mg2(hipStream_t s, Desc a, Desc b) {
    Descs D{}; D.d[0] = a; D.d[1] = b; D.nd = 2;
    mg_kernel<<<a.nblocks + b.nblocks, TPB, 0, s>>>(D);
}
static void mg3(hipStream_t s, Desc a, Desc b, Desc c) {
    Descs D{}; D.d[0] = a; D.d[1] = b; D.d[2] = c; D.nd = 3;
    mg_kernel<<<a.nblocks + b.nblocks + c.nblocks, TPB, 0, s>>>(D);
}

extern "C" void kernel_launch(void* const* d_in, const int* in_sizes, int n_in,
                              void* d_out, int out_size, void* d_ws, size_t ws_size,
                              hipStream_t stream) {
    const float* center    = (const float*)d_in[0];
    const float* corner    = (const float*)d_in[1];
    const float* normal    = (const float*)d_in[2];
    const int*   neighbour = (const int*)  d_in[3];
    const float* sp_W1 = (const float*)d_in[4];
    const float* sp_b1 = (const float*)d_in[5];
    const float* sp_W2 = (const float*)d_in[6];
    const float* sp_b2 = (const float*)d_in[7];
    const float* frc_Wc = (const float*)d_in[8];
    const float* frc_bc = (const float*)d_in[9];
    const float* frc_W3 = (const float*)d_in[10];
    const float* frc_b3 = (const float*)d_in[11];
    const float* frc_W4 = (const float*)d_in[12];
    const float* frc_b4 = (const float*)d_in[13];
    const float* kc_kernel = (const float*)d_in[14];
    const float* st_W1 = (const float*)d_in[15];
    const float* st_b1 = (const float*)d_in[16];
    const float* st_W2 = (const float*)d_in[17];
    const float* st_b2 = (const float*)d_in[18];
    const float* c1_W1 = (const float*)d_in[19];
    const float* c1_b1 = (const float*)d_in[20];
    const float* c1_W2 = (const float*)d_in[21];
    const float* c1_b2 = (const float*)d_in[22];
    const float* a1_W3 = (const float*)d_in[23];
    const float* a1_b3 = (const float*)d_in[24];
    const float* a1_W4 = (const float*)d_in[25];
    const float* a1_b4 = (const float*)d_in[26];
    const float* c2_W1 = (const float*)d_in[27];
    const float* c2_b1 = (const float*)d_in[28];
    const float* c2_W2 = (const float*)d_in[29];
    const float* c2_b2 = (const float*)d_in[30];
    const float* a2_W3 = (const float*)d_in[31];
    const float* a2_b3 = (const float*)d_in[32];
    const float* a2_W4 = (const float*)d_in[33];
    const float* a2_b4 = (const float*)d_in[34];
    const float* nt_W1 = (const float*)d_in[35];
    const float* nt_b1 = (const float*)d_in[36];
    const float* nt_W2 = (const float*)d_in[37];
    const float* nt_b2 = (const float*)d_in[38];
    const float* m2_W1 = (const float*)d_in[39];
    const float* m2_b1 = (const float*)d_in[40];
    const float* m2_W2 = (const float*)d_in[41];
    const float* m2_b2 = (const float*)d_in[42];
    const float* m3_W1 = (const float*)d_in[43];
    const float* m3_b1 = (const float*)d_in[44];
    const float* m3_W2 = (const float*)d_in[45];
    const float* m3_b2 = (const float*)d_in[46];
    const float* m3_W3 = (const float*)d_in[47];
    const float* m3_b3 = (const float*)d_in[48];

    float* ws = (float*)d_ws;
    float* C1IN  = ws + 512;           // [Y(512) | Z(1048)]
    float* Z     = ws + 1024;
    float* C1H   = ws + 2072;
    float* OUT12 = ws + 3672;          // [out1 | out2]
    float* A1H   = ws + 7768;
    float* C2H   = ws + 11864;
    float* OUT34 = ws + 15960;         // [out3 | out4]
    float* A2H   = ws + 24152;
    float* NTH   = ws + 28248;
    float* OUT6  = ws + 36440;         // [out5 | out3c | out1c]
    float* M2H   = ws + 50776;
    float* HBUF  = ws + 58968;
    float* M3H1  = ws + 67160;
    float* M3H2  = ws + 67672;

    // L1: faces + spatial chain + zeroing
    stage1_kernel<<<44, TPB, 0, stream>>>(center, corner, normal,
        sp_W1, sp_b1, sp_W2, sp_b2, frc_Wc, frc_bc, frc_W3, frc_b3,
        frc_W4, frc_b4, kc_kernel, st_W1, st_b1, st_W2, st_b2, ws);

    // L2: a1_W3 (agg1 from Z, 264 blk) + c1_W1 (x=[y|z], 120 blk)
    mg2(stream,
        gemv_desc(Z, a1_W3, A1H, a1_b3, 1048, 4096, 16, 2, 1, 0, 0, neighbour, 131),
        gemv_desc(C1IN, c1_W1, C1H, c1_b1, 1560, 1600, 26, 0));
    // L3: a1_W4 (256 blk) + c1_W2 (200 blk) -> OUT12
    mg2(stream,
        gemv_desc(A1H, a1_W4, OUT12 + 2048, a1_b4, 4096, 2048, 32, 1),
        gemv_desc(C1H, c1_W2, OUT12, c1_b2, 1600, 2048, 16, 1));
    // L4: c2_W1 (512 blk) + a2_W3 (agg2 from out2, 256 blk)
    mg2(stream,
        gemv_desc(OUT12, c2_W1, C2H, c2_b1, 4096, 4096, 32, 0),
        gemv_desc(OUT12 + 2048, a2_W3, A2H, a2_b3, 2048, 4096, 32, 2, 1, 0, 0, neighbour, 256));
    // L5: c2_W2 (512) + a2_W4 (512) -> OUT34 + copy out1 (2 blk)
    mg3(stream,
        gemv_desc(C2H, c2_W2, OUT34, c2_b2, 4096, 4096, 32, 1),
        gemv_desc(A2H, a2_W4, OUT34 + 4096, a2_b4, 4096, 4096, 32, 1),
        copy_desc(OUT12, OUT6 + 12288, 2048));
    // L6: nt_W1 (8 faces, 256 blk) + copy out3 (4 blk)
    mg2(stream,
        gemv_desc(OUT34, nt_W1, NTH, nt_b1, 1024, 1024, 32, 0, 8, 1024, 1024),
        copy_desc(OUT34, OUT6 + 8192, 4096));
    // L7: nt_W2 -> out5 (256 blk)
    mg1(stream,
        gemv_desc(NTH, nt_W2, OUT6, nt_b2, 1024, 1024, 32, 1, 8, 1024, 1024));
    // L8: m2_W1 (470 MB, 1024 blk = 4/CU)
    mg1(stream, gemv_desc(OUT6, m2_W1, M2H, m2_b1, 14336, 8192, 112, 0));
    // L9: m2_W2 (268 MB, 512 blk = 2/CU)
    mg1(stream, gemv_desc(M2H, m2_W2, HBUF, m2_b2, 8192, 8192, 128, 1));
    // L10: m3_W1 with inline maxpool over 8 faces (128 blk)
    mg1(stream, gemv_desc(HBUF, m3_W1, M3H1, m3_b1, 1024, 512, 8, 3));
    // L11: m3_W2 (64 blk)
    mg1(stream, gemv_desc(M3H1, m3_W2, M3H2, m3_b2, 512, 256, 8, 1));
    // L12: head
    head_kernel<<<1, 64, 0, stream>>>(M3H2, m3_W3, m3_b3, (float*)d_out);
}

// Round 9
// 303.013 us; speedup vs baseline: 2.9929x; 1.3026x over previous
//
#include <hip/hip_runtime.h>
#include <cstdint>

#define TPB 256
typedef __attribute__((ext_vector_type(4))) float f4;

// ---------------------------------------------------------------------------
// Workspace layout (floats):
//   Y     @   512 (512)    C1IN = [Y|Z] @ 512 (1560)
//   Z     @  1024 (1048)
//   C1H   @  2072 (1600)
//   OUT12 @  3672 (4096)   [out1 | out2]
//   A1H   @  7768 (4096)
//   C2H   @ 11864 (4096)
//   OUT34 @ 15960 (8192)   [out3 | out4]
//   A2H   @ 24152 (4096)
//   NTH   @ 28248 (8192)
//   OUT6  @ 36440 (14336)  [out5 | out3copy | out1copy]
//   M2H   @ 50776 (8192)
//   HBUF  @ 58968 (8192)
//   M3H1  @ 67160 (512)
//   M3H2  @ 67672 (256)
//   end   @ 67928
// Zero range (atomic-accumulated buffers): [2072, 67928)
// ---------------------------------------------------------------------------

__global__ __launch_bounds__(TPB) void stage1_kernel(
    const float* __restrict__ center, const float* __restrict__ corner,
    const float* __restrict__ normal,
    const float* __restrict__ spW1, const float* __restrict__ spb1,
    const float* __restrict__ spW2, const float* __restrict__ spb2,
    const float* __restrict__ Wc, const float* __restrict__ bc,
    const float* __restrict__ W3, const float* __restrict__ b3,
    const float* __restrict__ W4, const float* __restrict__ b4,
    const float* __restrict__ kck,
    const float* __restrict__ stW1, const float* __restrict__ stb1,
    const float* __restrict__ stW2, const float* __restrict__ stb2,
    float* __restrict__ ws) {
    int tid = threadIdx.x;
    int b = blockIdx.x;
    if (b < 8) {
        // ---- one face per block: FRC conv+mlp, kernel correlation, st MLP
        int f = b;
        __shared__ float sc[9], sn[3], sm[32], shh[64], sf[131], sh2[131];
        if (tid < 9) sc[tid] = corner[f * 9 + tid];
        if (tid < 3) { sn[tid] = normal[f * 3 + tid]; sf[tid] = normal[f * 3 + tid]; }
        __syncthreads();
        if (tid < 32) {                       // conv over 3 corner pairs, mean
            float acc = 0.f;
            for (int p = 0; p < 3; ++p) {
                const float* a  = &sc[3 * p];
                const float* b2 = &sc[3 * ((p + 1) % 3)];
                float d = bc[tid];
                for (int k = 0; k < 3; ++k)
                    d += a[k] * Wc[tid * 6 + k] + b2[k] * Wc[tid * 6 + 3 + k];
                acc += d;
            }
            sm[tid] = acc * (1.f / 3.f);
        }
        __syncthreads();
        if (tid < 64) {                       // frc hidden (32 -> 64), relu
            float h = b3[tid];
            for (int o = 0; o < 32; ++o) h = fmaf(sm[o], W3[o * 64 + tid], h);
            shh[tid] = fmaxf(h, 0.f);
        }
        if (tid < 64) {                       // kernel correlation -> sf[3+tid]
            float s = 0.f;
            for (int l = 0; l < 4; ++l) {
                float dx = sn[0] - kck[(tid * 4 + l) * 3 + 0];
                float dy = sn[1] - kck[(tid * 4 + l) * 3 + 1];
                float dz = sn[2] - kck[(tid * 4 + l) * 3 + 2];
                s += expf(-(dx * dx + dy * dy + dz * dz));
            }
            sf[3 + tid] = s * (1.f / 32.f);
        }
        __syncthreads();
        if (tid < 64) {                       // frc out (64 -> 64) -> sf[67+tid]
            float v = b4[tid];
            for (int k = 0; k < 64; ++k) v = fmaf(shh[k], W4[k * 64 + tid], v);
            sf[67 + tid] = v;
        }
        __syncthreads();
        if (tid < 131) {                      // st hidden, relu
            float a = stb1[tid];
            for (int k = 0; k < 131; ++k) a = fmaf(sf[k], stW1[k * 131 + tid], a);
            sh2[tid] = fmaxf(a, 0.f);
        }
        __syncthreads();
        if (tid < 131) {                      // st out -> Z
            float a = stb2[tid];
            for (int k = 0; k < 131; ++k) a = fmaf(sh2[k], stW2[k * 131 + tid], a);
            ws[1024 + f * 131 + tid] = a;
        }
    } else if (b < 12) {
        // ---- spatial chain: T1 = relu(center@spW1+b1) in LDS; y = T1@spW2+b2
        int bs = b - 8;
        __shared__ float sctr[24], st1[512];
        if (tid < 24) sctr[tid] = center[tid];
        __syncthreads();
        for (int j = tid; j < 512; j += TPB) {
            float a = spb1[j];
            for (int i = 0; i < 24; ++i) a = fmaf(sctr[i], spW1[i * 512 + j], a);
            st1[j] = fmaxf(a, 0.f);
        }
        __syncthreads();
        if (tid < 128) {
            int j = bs * 128 + tid;
            float a = spb2[j];
            for (int k = 0; k < 512; ++k) a = fmaf(st1[k], spW2[k * 512 + j], a);
            ws[512 + j] = a;                  // Y, direct write
        }
    } else {
        // ---- zero the atomic-accumulated region [2072, 67928)
        int zb = b - 12;                      // 0..31
        f4 z4 = {0.f, 0.f, 0.f, 0.f};
        f4* p = (f4*)(ws + 2072);
        int n4 = (67928 - 2072) / 4;          // 16464
        for (int i = zb * TPB + tid; i < n4; i += 32 * TPB) p[i] = z4;
    }
}

// ---------------------------------------------------------------------------
// Multi-GEMV: up to 3 descriptors per launch. Split-K with HW f32 atomics
// onto zeroed buffers; bias folded into the ci==0 chunk; x-staging fuses
// relu / neighbour-agg / maxpool; op 4 = plain float4 copy.
// op 5 = relu-in SPARSE: compact nonzero rows of relu(x) (deterministic
// ballot-based, ordered) and stream only those W rows (~50% byte skip).
// ---------------------------------------------------------------------------
struct Desc {
    const float* x; const float* W; float* out; const float* bias;
    const int* nb;
    int in_dim, out_dim, chunk, ntile, nchunk, nvec, xs, os;
    int op;        // 0 direct, 1 relu-in, 2 agg, 3 maxpool8, 4 copy, 5 relu-sparse
    int aggdim;
    int nblocks;
};
struct Descs { Desc d[3]; int nd; };

__global__ __launch_bounds__(TPB) void mg_kernel(Descs D) {
    int bid = blockIdx.x;
    int di = 0;
    while (di + 1 < D.nd && bid >= D.d[di].nblocks) { bid -= D.d[di].nblocks; ++di; }
    Desc d = D.d[di];
    int tid = threadIdx.x;
    if (d.op == 4) {                          // copy
        int i = bid * TPB + tid;
        int n4 = d.in_dim >> 2;
        if (i < n4) ((f4*)d.out)[i] = ((const f4*)d.x)[i];
        return;
    }
    __shared__ float sx[512];
    __shared__ float sval[512];
    __shared__ unsigned short sidx[512];
    __shared__ int segc[10];
    int per = d.ntile * d.nchunk;
    int vec = bid / per;
    int r = bid - vec * per;
    int ci = r / d.ntile;
    int tile = r - ci * d.ntile;
    const float* x = d.x + (size_t)vec * d.xs;
    float* out = d.out + (size_t)vec * d.os;
    int row0 = ci * d.chunk;
    int rows = min(d.chunk, d.in_dim - row0);
    for (int t = tid; t < rows; t += TPB) {
        int idx = row0 + t;
        float v;
        if (d.op == 2) {
            int i = idx / d.aggdim, k = idx - i * d.aggdim;
            const int* nb = d.nb + i * 3;
            v = 0.25f * (x[i * d.aggdim + k] + x[nb[0] * d.aggdim + k] +
                         x[nb[1] * d.aggdim + k] + x[nb[2] * d.aggdim + k]);
        } else if (d.op == 3) {
            v = x[idx];
#pragma unroll
            for (int f = 1; f < 8; ++f) v = fmaxf(v, x[f * d.in_dim + idx]);
        } else {
            v = x[idx];
            if (d.op == 1 || d.op == 5) v = fmaxf(v, 0.f);
        }
        sx[t] = v;
    }
    __syncthreads();

    if (d.op == 5) {
        // ---- deterministic ordered compaction of nonzero rows ----
        int wave = tid >> 6, lane = tid & 63;
        int nseg = (rows + 63) >> 6;
        for (int s = wave; s < nseg; s += 4) {
            int t = s * 64 + lane;
            bool p = (t < rows) && (sx[t] > 0.f);
            unsigned long long m = __ballot(p);
            if (lane == 0) segc[s] = __popcll(m);
        }
        __syncthreads();
        if (tid == 0) {
            int acc = 0;
            for (int s = 0; s < nseg; ++s) { int c = segc[s]; segc[s] = acc; acc += c; }
            segc[nseg] = acc;
        }
        __syncthreads();
        for (int s = wave; s < nseg; s += 4) {
            int t = s * 64 + lane;
            bool p = (t < rows) && (sx[t] > 0.f);
            unsigned long long m = __ballot(p);
            int rk = __popcll(m & ((1ull << lane) - 1ull));
            if (p) {
                int o = segc[s] + rk;
                sval[o] = sx[t];
                sidx[o] = (unsigned short)t;
            }
        }
        __syncthreads();
        int cnt = segc[nseg];
        int j = tile * (TPB * 4) + tid * 4;
        if (j >= d.out_dim) return;
        const float* wb = d.W + j;
        float ax = 0.f, ay = 0.f, az = 0.f, aw = 0.f;
#pragma unroll 8
        for (int t = 0; t < cnt; ++t) {
            float xv = sval[t];
            f4 w = *(const f4*)(wb + (size_t)(row0 + (int)sidx[t]) * d.out_dim);
            ax = fmaf(xv, w[0], ax); ay = fmaf(xv, w[1], ay);
            az = fmaf(xv, w[2], az); aw = fmaf(xv, w[3], aw);
        }
        if (ci == 0 && d.bias) {
            ax += d.bias[j]; ay += d.bias[j + 1];
            az += d.bias[j + 2]; aw += d.bias[j + 3];
        }
        unsafeAtomicAdd(&out[j + 0], ax);
        unsafeAtomicAdd(&out[j + 1], ay);
        unsafeAtomicAdd(&out[j + 2], az);
        unsafeAtomicAdd(&out[j + 3], aw);
        return;
    }

    int j = tile * (TPB * 4) + tid * 4;
    if (j >= d.out_dim) return;
    const float* wp = d.W + (size_t)row0 * d.out_dim + j;
    float ax = 0.f, ay = 0.f, az = 0.f, aw = 0.f;
#pragma unroll 16
    for (int t = 0; t < rows; ++t) {
        f4 w = *(const f4*)wp;
        float xv = sx[t];
        ax = fmaf(xv, w[0], ax); ay = fmaf(xv, w[1], ay);
        az = fmaf(xv, w[2], az); aw = fmaf(xv, w[3], aw);
        wp += d.out_dim;
    }
    if (ci == 0 && d.bias) {
        ax += d.bias[j]; ay += d.bias[j + 1]; az += d.bias[j + 2]; aw += d.bias[j + 3];
    }
    unsafeAtomicAdd(&out[j + 0], ax);
    unsafeAtomicAdd(&out[j + 1], ay);
    unsafeAtomicAdd(&out[j + 2], az);
    unsafeAtomicAdd(&out[j + 3], aw);
}

// head: logits = relu(M3H2) @ m3_W3 + b3   (256 -> 40)
__global__ __launch_bounds__(64) void head_kernel(
    const float* __restrict__ x, const float* __restrict__ W,
    const float* __restrict__ b, float* __restrict__ out) {
    __shared__ float sx[256];
    int tid = threadIdx.x;
    for (int k = tid; k < 256; k += 64) sx[k] = fmaxf(x[k], 0.f);
    __syncthreads();
    if (tid < 40) {
        float a = b[tid];
        for (int k = 0; k < 256; ++k) a = fmaf(sx[k], W[k * 40 + tid], a);
        out[tid] = a;
    }
}

// ---------------------------------------------------------------------------
static Desc gemv_desc(const float* x, const float* W, float* out, const float* bias,
                      int in, int outd, int chunk, int op,
                      int nvec = 1, int xs = 0, int os = 0,
                      const int* nb = nullptr, int aggdim = 0) {
    Desc d{};
    d.x = x; d.W = W; d.out = out; d.bias = bias; d.nb = nb;
    d.in_dim = in; d.out_dim = outd; d.chunk = chunk;
    d.ntile = (outd + TPB * 4 - 1) / (TPB * 4);
    d.nchunk = (in + chunk - 1) / chunk;
    d.nvec = nvec; d.xs = xs; d.os = os;
    d.op = op; d.aggdim = aggdim;
    d.nblocks = d.ntile * d.nchunk * nvec;
    return d;
}
static Desc copy_desc(const float* src, float* dst, int n) {
    Desc d{};
    d.x = src; d.out = dst; d.in_dim = n; d.op = 4;
    d.nblocks = (n / 4 + TPB - 1) / TPB;
    return d;
}
static void mg1(hipStream_t s, Desc a) {
    Descs D{}; D.d[0] = a; D.nd = 1;
    mg_kernel<<<a.nblocks, TPB, 0, s>>>(D);
}
static void mg2(hipStream_t s, Desc a, Desc b) {
    Descs D{}; D.d[0] = a; D.d[1] = b; D.nd = 2;
    mg_kernel<<<a.nblocks + b.nblocks, TPB, 0, s>>>(D);
}
static void mg3(hipStream_t s, Desc a, Desc b, Desc c) {
    Descs D{}; D.d[0] = a; D.d[1] = b; D.d[2] = c; D.nd = 3;
    mg_kernel<<<a.nblocks + b.nblocks + c.nblocks, TPB, 0, s>>>(D);
}

extern "C" void kernel_launch(void* const* d_in, const int* in_sizes, int n_in,
                              void* d_out, int out_size, void* d_ws, size_t ws_size,
                              hipStream_t stream) {
    const float* center    = (const float*)d_in[0];
    const float* corner    = (const float*)d_in[1];
    const float* normal    = (const float*)d_in[2];
    const int*   neighbour = (const int*)  d_in[3];
    const float* sp_W1 = (const float*)d_in[4];
    const float* sp_b1 = (const float*)d_in[5];
    const float* sp_W2 = (const float*)d_in[6];
    const float* sp_b2 = (const float*)d_in[7];
    const float* frc_Wc = (const float*)d_in[8];
    const float* frc_bc = (const float*)d_in[9];
    const float* frc_W3 = (const float*)d_in[10];
    const float* frc_b3 = (const float*)d_in[11];
    const float* frc_W4 = (const float*)d_in[12];
    const float* frc_b4 = (const float*)d_in[13];
    const float* kc_kernel = (const float*)d_in[14];
    const float* st_W1 = (const float*)d_in[15];
    const float* st_b1 = (const float*)d_in[16];
    const float* st_W2 = (const float*)d_in[17];
    const float* st_b2 = (const float*)d_in[18];
    const float* c1_W1 = (const float*)d_in[19];
    const float* c1_b1 = (const float*)d_in[20];
    const float* c1_W2 = (const float*)d_in[21];
    const float* c1_b2 = (const float*)d_in[22];
    const float* a1_W3 = (const float*)d_in[23];
    const float* a1_b3 = (const float*)d_in[24];
    const float* a1_W4 = (const float*)d_in[25];
    const float* a1_b4 = (const float*)d_in[26];
    const float* c2_W1 = (const float*)d_in[27];
    const float* c2_b1 = (const float*)d_in[28];
    const float* c2_W2 = (const float*)d_in[29];
    const float* c2_b2 = (const float*)d_in[30];
    const float* a2_W3 = (const float*)d_in[31];
    const float* a2_b3 = (const float*)d_in[32];
    const float* a2_W4 = (const float*)d_in[33];
    const float* a2_b4 = (const float*)d_in[34];
    const float* nt_W1 = (const float*)d_in[35];
    const float* nt_b1 = (const float*)d_in[36];
    const float* nt_W2 = (const float*)d_in[37];
    const float* nt_b2 = (const float*)d_in[38];
    const float* m2_W1 = (const float*)d_in[39];
    const float* m2_b1 = (const float*)d_in[40];
    const float* m2_W2 = (const float*)d_in[41];
    const float* m2_b2 = (const float*)d_in[42];
    const float* m3_W1 = (const float*)d_in[43];
    const float* m3_b1 = (const float*)d_in[44];
    const float* m3_W2 = (const float*)d_in[45];
    const float* m3_b2 = (const float*)d_in[46];
    const float* m3_W3 = (const float*)d_in[47];
    const float* m3_b3 = (const float*)d_in[48];

    float* ws = (float*)d_ws;
    float* C1IN  = ws + 512;           // [Y(512) | Z(1048)]
    float* Z     = ws + 1024;
    float* C1H   = ws + 2072;
    float* OUT12 = ws + 3672;          // [out1 | out2]
    float* A1H   = ws + 7768;
    float* C2H   = ws + 11864;
    float* OUT34 = ws + 15960;         // [out3 | out4]
    float* A2H   = ws + 24152;
    float* NTH   = ws + 28248;
    float* OUT6  = ws + 36440;         // [out5 | out3c | out1c]
    float* M2H   = ws + 50776;
    float* HBUF  = ws + 58968;
    float* M3H1  = ws + 67160;
    float* M3H2  = ws + 67672;

    // L1: faces + spatial chain + zeroing
    stage1_kernel<<<44, TPB, 0, stream>>>(center, corner, normal,
        sp_W1, sp_b1, sp_W2, sp_b2, frc_Wc, frc_bc, frc_W3, frc_b3,
        frc_W4, frc_b4, kc_kernel, st_W1, st_b1, st_W2, st_b2, ws);

    // L2: c1_W1 (x=[y|z]) + a1_W3 (agg1 inline from Z)   [R3-exact chunks]
    mg2(stream,
        gemv_desc(C1IN, c1_W1, C1H, c1_b1, 1560, 1600, 26, 0),
        gemv_desc(Z, a1_W3, A1H, a1_b3, 1048, 4096, 17, 2, 1, 0, 0, neighbour, 131));
    // L3: c1_W2 (relu-sparse) + a1_W4 (relu-sparse)
    mg2(stream,
        gemv_desc(C1H, c1_W2, OUT12, c1_b2, 1600, 2048, 28, 5),
        gemv_desc(A1H, a1_W4, OUT12 + 2048, a1_b4, 4096, 2048, 64, 5));
    // L4: c2_W1 + a2_W3 (agg2 inline from out2)
    mg2(stream,
        gemv_desc(OUT12, c2_W1, C2H, c2_b1, 4096, 4096, 64, 0),
        gemv_desc(OUT12 + 2048, a2_W3, A2H, a2_b3, 2048, 4096, 32, 2, 1, 0, 0, neighbour, 256));
    // L5: c2_W2 (sparse) + a2_W4 (sparse) + copy out1 -> OUT6 tail
    mg3(stream,
        gemv_desc(C2H, c2_W2, OUT34, c2_b2, 4096, 4096, 64, 5),
        gemv_desc(A2H, a2_W4, OUT34 + 4096, a2_b4, 4096, 4096, 64, 5),
        copy_desc(OUT12, OUT6 + 12288, 2048));
    // L6: nt_W1 (8 faces) + copy out3 -> OUT6 mid
    mg2(stream,
        gemv_desc(OUT34, nt_W1, NTH, nt_b1, 1024, 1024, 64, 0, 8, 1024, 1024),
        copy_desc(OUT34, OUT6 + 8192, 4096));
    // L7: nt_W2 -> out5 (weights L2-cached across 8 faces; keep dense relu)
    mg1(stream,
        gemv_desc(NTH, nt_W2, OUT6, nt_b2, 1024, 1024, 64, 1, 8, 1024, 1024));
    // L8: m2_W1 (470 MB, input not relu'd -> dense)
    mg1(stream, gemv_desc(OUT6, m2_W1, M2H, m2_b1, 14336, 8192, 448, 0));
    // L9: m2_W2 (268 MB, relu-sparse -> ~134 MB)
    mg1(stream, gemv_desc(M2H, m2_W2, HBUF, m2_b2, 8192, 8192, 256, 5));
    // L10: m3_W1 with inline maxpool over 8 faces
    mg1(stream, gemv_desc(HBUF, m3_W1, M3H1, m3_b1, 1024, 512, 16, 3));
    // L11: m3_W2
    mg1(stream, gemv_desc(M3H1, m3_W2, M3H2, m3_b2, 512, 256, 8, 1));
    // L12: head
    head_kernel<<<1, 64, 0, stream>>>(M3H2, m3_W3, m3_b3, (float*)d_out);
}

// Round 10
// 267.560 us; speedup vs baseline: 3.3895x; 1.1325x over previous
//
#include <hip/hip_runtime.h>
#include <cstdint>

#define TPB 256
typedef __attribute__((ext_vector_type(4))) float f4;

// ---------------------------------------------------------------------------
// Workspace layout (floats):
//   Y     @   512 (512)    C1IN = [Y|Z] @ 512 (1560)
//   Z     @  1024 (1048)
//   C1H   @  2072 (1600)
//   OUT12 @  3672 (4096)   [out1 | out2]
//   A1H   @  7768 (4096)
//   C2H   @ 11864 (4096)
//   OUT34 @ 15960 (8192)   [out3 | out4]
//   A2H   @ 24152 (4096)
//   NTH   @ 28248 (8192)
//   OUT6  @ 36440 (14336)  [out5 | out3copy | out1copy]
//   M2H   @ 50776 (8192)
//   HBUF  @ 58968 (8192)
//   M3H1  @ 67160 (512)
//   M3H2  @ 67672 (256)   (unused since tail merge; still zeroed)
//   end   @ 67928
// Zero range (atomic-accumulated buffers): [2072, 67928)
// ---------------------------------------------------------------------------

__global__ __launch_bounds__(TPB) void stage1_kernel(
    const float* __restrict__ center, const float* __restrict__ corner,
    const float* __restrict__ normal,
    const float* __restrict__ spW1, const float* __restrict__ spb1,
    const float* __restrict__ spW2, const float* __restrict__ spb2,
    const float* __restrict__ Wc, const float* __restrict__ bc,
    const float* __restrict__ W3, const float* __restrict__ b3,
    const float* __restrict__ W4, const float* __restrict__ b4,
    const float* __restrict__ kck,
    const float* __restrict__ stW1, const float* __restrict__ stb1,
    const float* __restrict__ stW2, const float* __restrict__ stb2,
    float* __restrict__ ws) {
    int tid = threadIdx.x;
    int b = blockIdx.x;
    if (b < 8) {
        // ---- one face per block: FRC conv+mlp, kernel correlation, st MLP
        int f = b;
        __shared__ float sc[9], sn[3], sm[32], shh[64], sf[131], sh2[131];
        if (tid < 9) sc[tid] = corner[f * 9 + tid];
        if (tid < 3) { sn[tid] = normal[f * 3 + tid]; sf[tid] = normal[f * 3 + tid]; }
        __syncthreads();
        if (tid < 32) {                       // conv over 3 corner pairs, mean
            float acc = 0.f;
            for (int p = 0; p < 3; ++p) {
                const float* a  = &sc[3 * p];
                const float* b2 = &sc[3 * ((p + 1) % 3)];
                float d = bc[tid];
                for (int k = 0; k < 3; ++k)
                    d += a[k] * Wc[tid * 6 + k] + b2[k] * Wc[tid * 6 + 3 + k];
                acc += d;
            }
            sm[tid] = acc * (1.f / 3.f);
        }
        __syncthreads();
        if (tid < 64) {                       // frc hidden (32 -> 64), relu
            float h = b3[tid];
            for (int o = 0; o < 32; ++o) h = fmaf(sm[o], W3[o * 64 + tid], h);
            shh[tid] = fmaxf(h, 0.f);
        }
        if (tid < 64) {                       // kernel correlation -> sf[3+tid]
            float s = 0.f;
            for (int l = 0; l < 4; ++l) {
                float dx = sn[0] - kck[(tid * 4 + l) * 3 + 0];
                float dy = sn[1] - kck[(tid * 4 + l) * 3 + 1];
                float dz = sn[2] - kck[(tid * 4 + l) * 3 + 2];
                s += expf(-(dx * dx + dy * dy + dz * dz));
            }
            sf[3 + tid] = s * (1.f / 32.f);
        }
        __syncthreads();
        if (tid < 64) {                       // frc out (64 -> 64) -> sf[67+tid]
            float v = b4[tid];
            for (int k = 0; k < 64; ++k) v = fmaf(shh[k], W4[k * 64 + tid], v);
            sf[67 + tid] = v;
        }
        __syncthreads();
        if (tid < 131) {                      // st hidden, relu
            float a = stb1[tid];
            for (int k = 0; k < 131; ++k) a = fmaf(sf[k], stW1[k * 131 + tid], a);
            sh2[tid] = fmaxf(a, 0.f);
        }
        __syncthreads();
        if (tid < 131) {                      // st out -> Z
            float a = stb2[tid];
            for (int k = 0; k < 131; ++k) a = fmaf(sh2[k], stW2[k * 131 + tid], a);
            ws[1024 + f * 131 + tid] = a;
        }
    } else if (b < 12) {
        // ---- spatial chain: T1 = relu(center@spW1+b1) in LDS; y = T1@spW2+b2
        int bs = b - 8;
        __shared__ float sctr[24], st1[512];
        if (tid < 24) sctr[tid] = center[tid];
        __syncthreads();
        for (int j = tid; j < 512; j += TPB) {
            float a = spb1[j];
            for (int i = 0; i < 24; ++i) a = fmaf(sctr[i], spW1[i * 512 + j], a);
            st1[j] = fmaxf(a, 0.f);
        }
        __syncthreads();
        if (tid < 128) {
            int j = bs * 128 + tid;
            float a = spb2[j];
            for (int k = 0; k < 512; ++k) a = fmaf(st1[k], spW2[k * 512 + j], a);
            ws[512 + j] = a;                  // Y, direct write
        }
    } else {
        // ---- zero the atomic-accumulated region [2072, 67928)
        int zb = b - 12;                      // 0..31
        f4 z4 = {0.f, 0.f, 0.f, 0.f};
        f4* p = (f4*)(ws + 2072);
        int n4 = (67928 - 2072) / 4;          // 16464
        for (int i = zb * TPB + tid; i < n4; i += 32 * TPB) p[i] = z4;
    }
}

// ---------------------------------------------------------------------------
// Multi-GEMV: up to 3 descriptors per launch. Split-K with HW f32 atomics
// onto zeroed buffers; bias folded into the ci==0 chunk; x-staging fuses
// relu / neighbour-agg / maxpool; op 4 = plain float4 copy.
// op 5 = relu-in SPARSE: compact nonzero rows of relu(x) (deterministic
// ballot-based, ordered) and stream only those W rows (~50% byte skip).
// nt=1: nontemporal weight loads (single-use giant streams; don't thrash L2).
// ---------------------------------------------------------------------------
struct Desc {
    const float* x; const float* W; float* out; const float* bias;
    const int* nb;
    int in_dim, out_dim, chunk, ntile, nchunk, nvec, xs, os;
    int op;        // 0 direct, 1 relu-in, 2 agg, 3 maxpool8, 4 copy, 5 relu-sparse
    int aggdim;
    int nt;
    int nblocks;
};
struct Descs { Desc d[3]; int nd; };

__global__ __launch_bounds__(TPB) void mg_kernel(Descs D) {
    int bid = blockIdx.x;
    int di = 0;
    while (di + 1 < D.nd && bid >= D.d[di].nblocks) { bid -= D.d[di].nblocks; ++di; }
    Desc d = D.d[di];
    int tid = threadIdx.x;
    if (d.op == 4) {                          // copy
        int i = bid * TPB + tid;
        int n4 = d.in_dim >> 2;
        if (i < n4) ((f4*)d.out)[i] = ((const f4*)d.x)[i];
        return;
    }
    __shared__ float sx[512];
    __shared__ float sval[512];
    __shared__ unsigned short sidx[512];
    __shared__ int segc[10];
    int per = d.ntile * d.nchunk;
    int vec = bid / per;
    int r = bid - vec * per;
    int ci = r / d.ntile;
    int tile = r - ci * d.ntile;
    const float* x = d.x + (size_t)vec * d.xs;
    float* out = d.out + (size_t)vec * d.os;
    int row0 = ci * d.chunk;
    int rows = min(d.chunk, d.in_dim - row0);
    for (int t = tid; t < rows; t += TPB) {
        int idx = row0 + t;
        float v;
        if (d.op == 2) {
            int i = idx / d.aggdim, k = idx - i * d.aggdim;
            const int* nb = d.nb + i * 3;
            v = 0.25f * (x[i * d.aggdim + k] + x[nb[0] * d.aggdim + k] +
                         x[nb[1] * d.aggdim + k] + x[nb[2] * d.aggdim + k]);
        } else if (d.op == 3) {
            v = x[idx];
#pragma unroll
            for (int f = 1; f < 8; ++f) v = fmaxf(v, x[f * d.in_dim + idx]);
        } else {
            v = x[idx];
            if (d.op == 1 || d.op == 5) v = fmaxf(v, 0.f);
        }
        sx[t] = v;
    }
    __syncthreads();

    if (d.op == 5) {
        // ---- deterministic ordered compaction of nonzero rows ----
        int wave = tid >> 6, lane = tid & 63;
        int nseg = (rows + 63) >> 6;
        for (int s = wave; s < nseg; s += 4) {
            int t = s * 64 + lane;
            bool p = (t < rows) && (sx[t] > 0.f);
            unsigned long long m = __ballot(p);
            if (lane == 0) segc[s] = __popcll(m);
        }
        __syncthreads();
        if (tid == 0) {
            int acc = 0;
            for (int s = 0; s < nseg; ++s) { int c = segc[s]; segc[s] = acc; acc += c; }
            segc[nseg] = acc;
        }
        __syncthreads();
        for (int s = wave; s < nseg; s += 4) {
            int t = s * 64 + lane;
            bool p = (t < rows) && (sx[t] > 0.f);
            unsigned long long m = __ballot(p);
            int rk = __popcll(m & ((1ull << lane) - 1ull));
            if (p) {
                int o = segc[s] + rk;
                sval[o] = sx[t];
                sidx[o] = (unsigned short)t;
            }
        }
        __syncthreads();
        int cnt = segc[nseg];
        int j = tile * (TPB * 4) + tid * 4;
        if (j >= d.out_dim) return;
        const float* wb = d.W + j;
        float ax = 0.f, ay = 0.f, az = 0.f, aw = 0.f;
        if (d.nt) {
#pragma unroll 8
            for (int t = 0; t < cnt; ++t) {
                float xv = sval[t];
                f4 w = __builtin_nontemporal_load(
                    (const f4*)(wb + (size_t)(row0 + (int)sidx[t]) * d.out_dim));
                ax = fmaf(xv, w[0], ax); ay = fmaf(xv, w[1], ay);
                az = fmaf(xv, w[2], az); aw = fmaf(xv, w[3], aw);
            }
        } else {
#pragma unroll 8
            for (int t = 0; t < cnt; ++t) {
                float xv = sval[t];
                f4 w = *(const f4*)(wb + (size_t)(row0 + (int)sidx[t]) * d.out_dim);
                ax = fmaf(xv, w[0], ax); ay = fmaf(xv, w[1], ay);
                az = fmaf(xv, w[2], az); aw = fmaf(xv, w[3], aw);
            }
        }
        if (ci == 0 && d.bias) {
            ax += d.bias[j]; ay += d.bias[j + 1];
            az += d.bias[j + 2]; aw += d.bias[j + 3];
        }
        unsafeAtomicAdd(&out[j + 0], ax);
        unsafeAtomicAdd(&out[j + 1], ay);
        unsafeAtomicAdd(&out[j + 2], az);
        unsafeAtomicAdd(&out[j + 3], aw);
        return;
    }

    int j = tile * (TPB * 4) + tid * 4;
    if (j >= d.out_dim) return;
    const float* wp = d.W + (size_t)row0 * d.out_dim + j;
    float ax = 0.f, ay = 0.f, az = 0.f, aw = 0.f;
    if (d.nt) {
#pragma unroll 16
        for (int t = 0; t < rows; ++t) {
            f4 w = __builtin_nontemporal_load((const f4*)wp);
            float xv = sx[t];
            ax = fmaf(xv, w[0], ax); ay = fmaf(xv, w[1], ay);
            az = fmaf(xv, w[2], az); aw = fmaf(xv, w[3], aw);
            wp += d.out_dim;
        }
    } else {
#pragma unroll 16
        for (int t = 0; t < rows; ++t) {
            f4 w = *(const f4*)wp;
            float xv = sx[t];
            ax = fmaf(xv, w[0], ax); ay = fmaf(xv, w[1], ay);
            az = fmaf(xv, w[2], az); aw = fmaf(xv, w[3], aw);
            wp += d.out_dim;
        }
    }
    if (ci == 0 && d.bias) {
        ax += d.bias[j]; ay += d.bias[j + 1]; az += d.bias[j + 2]; aw += d.bias[j + 3];
    }
    unsafeAtomicAdd(&out[j + 0], ax);
    unsafeAtomicAdd(&out[j + 1], ay);
    unsafeAtomicAdd(&out[j + 2], az);
    unsafeAtomicAdd(&out[j + 3], aw);
}

// tail: M3H2 = relu(M3H1)@m3_W2+b2 (redundant per block), logit j per block.
// 40 blocks x 256 threads; deterministic tree reduction.
__global__ __launch_bounds__(TPB) void tail_kernel(
    const float* __restrict__ m3h1, const float* __restrict__ W2,
    const float* __restrict__ b2, const float* __restrict__ W3,
    const float* __restrict__ b3, float* __restrict__ out) {
    __shared__ float s1[512], red[256];
    int tid = threadIdx.x, j = blockIdx.x;
    for (int k = tid; k < 512; k += TPB) s1[k] = fmaxf(m3h1[k], 0.f);
    __syncthreads();
    float a = b2[tid];
    for (int i = 0; i < 512; ++i) a = fmaf(s1[i], W2[i * 256 + tid], a);
    a = fmaxf(a, 0.f);                        // relu(M3H2[tid])
    red[tid] = a * W3[tid * 40 + j];
    __syncthreads();
    for (int s = 128; s > 0; s >>= 1) {
        if (tid < s) red[tid] += red[tid + s];
        __syncthreads();
    }
    if (tid == 0) out[j] = red[0] + b3[j];
}

// ---------------------------------------------------------------------------
static Desc gemv_desc(const float* x, const float* W, float* out, const float* bias,
                      int in, int outd, int chunk, int op,
                      int nvec = 1, int xs = 0, int os = 0,
                      const int* nb = nullptr, int aggdim = 0, int nt = 0) {
    Desc d{};
    d.x = x; d.W = W; d.out = out; d.bias = bias; d.nb = nb;
    d.in_dim = in; d.out_dim = outd; d.chunk = chunk;
    d.ntile = (outd + TPB * 4 - 1) / (TPB * 4);
    d.nchunk = (in + chunk - 1) / chunk;
    d.nvec = nvec; d.xs = xs; d.os = os;
    d.op = op; d.aggdim = aggdim; d.nt = nt;
    d.nblocks = d.ntile * d.nchunk * nvec;
    return d;
}
static Desc copy_desc(const float* src, float* dst, int n) {
    Desc d{};
    d.x = src; d.out = dst; d.in_dim = n; d.op = 4;
    d.nblocks = (n / 4 + TPB - 1) / TPB;
    return d;
}
static void mg1(hipStream_t s, Desc a) {
    Descs D{}; D.d[0] = a; D.nd = 1;
    mg_kernel<<<a.nblocks, TPB, 0, s>>>(D);
}
static void mg2(hipStream_t s, Desc a, Desc b) {
    Descs D{}; D.d[0] = a; D.d[1] = b; D.nd = 2;
    mg_kernel<<<a.nblocks + b.nblocks, TPB, 0, s>>>(D);
}
static void mg3(hipStream_t s, Desc a, Desc b, Desc c) {
    Descs D{}; D.d[0] = a; D.d[1] = b; D.d[2] = c; D.nd = 3;
    mg_kernel<<<a.nblocks + b.nblocks + c.nblocks, TPB, 0, s>>>(D);
}

extern "C" void kernel_launch(void* const* d_in, const int* in_sizes, int n_in,
                              void* d_out, int out_size, void* d_ws, size_t ws_size,
                              hipStream_t stream) {
    const float* center    = (const float*)d_in[0];
    const float* corner    = (const float*)d_in[1];
    const float* normal    = (const float*)d_in[2];
    const int*   neighbour = (const int*)  d_in[3];
    const float* sp_W1 = (const float*)d_in[4];
    const float* sp_b1 = (const float*)d_in[5];
    const float* sp_W2 = (const float*)d_in[6];
    const float* sp_b2 = (const float*)d_in[7];
    const float* frc_Wc = (const float*)d_in[8];
    const float* frc_bc = (const float*)d_in[9];
    const float* frc_W3 = (const float*)d_in[10];
    const float* frc_b3 = (const float*)d_in[11];
    const float* frc_W4 = (const float*)d_in[12];
    const float* frc_b4 = (const float*)d_in[13];
    const float* kc_kernel = (const float*)d_in[14];
    const float* st_W1 = (const float*)d_in[15];
    const float* st_b1 = (const float*)d_in[16];
    const float* st_W2 = (const float*)d_in[17];
    const float* st_b2 = (const float*)d_in[18];
    const float* c1_W1 = (const float*)d_in[19];
    const float* c1_b1 = (const float*)d_in[20];
    const float* c1_W2 = (const float*)d_in[21];
    const float* c1_b2 = (const float*)d_in[22];
    const float* a1_W3 = (const float*)d_in[23];
    const float* a1_b3 = (const float*)d_in[24];
    const float* a1_W4 = (const float*)d_in[25];
    const float* a1_b4 = (const float*)d_in[26];
    const float* c2_W1 = (const float*)d_in[27];
    const float* c2_b1 = (const float*)d_in[28];
    const float* c2_W2 = (const float*)d_in[29];
    const float* c2_b2 = (const float*)d_in[30];
    const float* a2_W3 = (const float*)d_in[31];
    const float* a2_b3 = (const float*)d_in[32];
    const float* a2_W4 = (const float*)d_in[33];
    const float* a2_b4 = (const float*)d_in[34];
    const float* nt_W1 = (const float*)d_in[35];
    const float* nt_b1 = (const float*)d_in[36];
    const float* nt_W2 = (const float*)d_in[37];
    const float* nt_b2 = (const float*)d_in[38];
    const float* m2_W1 = (const float*)d_in[39];
    const float* m2_b1 = (const float*)d_in[40];
    const float* m2_W2 = (const float*)d_in[41];
    const float* m2_b2 = (const float*)d_in[42];
    const float* m3_W1 = (const float*)d_in[43];
    const float* m3_b1 = (const float*)d_in[44];
    const float* m3_W2 = (const float*)d_in[45];
    const float* m3_b2 = (const float*)d_in[46];
    const float* m3_W3 = (const float*)d_in[47];
    const float* m3_b3 = (const float*)d_in[48];

    float* ws = (float*)d_ws;
    float* C1IN  = ws + 512;           // [Y(512) | Z(1048)]
    float* Z     = ws + 1024;
    float* C1H   = ws + 2072;
    float* OUT12 = ws + 3672;          // [out1 | out2]
    float* A1H   = ws + 7768;
    float* C2H   = ws + 11864;
    float* OUT34 = ws + 15960;         // [out3 | out4]
    float* A2H   = ws + 24152;
    float* NTH   = ws + 28248;
    float* OUT6  = ws + 36440;         // [out5 | out3c | out1c]
    float* M2H   = ws + 50776;
    float* HBUF  = ws + 58968;
    float* M3H1  = ws + 67160;

    // L1: faces + spatial chain + zeroing
    stage1_kernel<<<44, TPB, 0, stream>>>(center, corner, normal,
        sp_W1, sp_b1, sp_W2, sp_b2, frc_Wc, frc_bc, frc_W3, frc_b3,
        frc_W4, frc_b4, kc_kernel, st_W1, st_b1, st_W2, st_b2, ws);

    // L2: c1_W1 (x=[y|z]) + a1_W3 (agg1 inline from Z)
    mg2(stream,
        gemv_desc(C1IN, c1_W1, C1H, c1_b1, 1560, 1600, 26, 0),
        gemv_desc(Z, a1_W3, A1H, a1_b3, 1048, 4096, 17, 2, 1, 0, 0, neighbour, 131));
    // L3: c1_W2 (relu-sparse) + a1_W4 (relu-sparse)
    mg2(stream,
        gemv_desc(C1H, c1_W2, OUT12, c1_b2, 1600, 2048, 28, 5),
        gemv_desc(A1H, a1_W4, OUT12 + 2048, a1_b4, 4096, 2048, 64, 5));
    // L4: c2_W1 + a2_W3 (agg2 inline from out2)
    mg2(stream,
        gemv_desc(OUT12, c2_W1, C2H, c2_b1, 4096, 4096, 64, 0),
        gemv_desc(OUT12 + 2048, a2_W3, A2H, a2_b3, 2048, 4096, 32, 2, 1, 0, 0, neighbour, 256));
    // L5: c2_W2 (sparse) + a2_W4 (sparse) + copy out1 -> OUT6 tail
    mg3(stream,
        gemv_desc(C2H, c2_W2, OUT34, c2_b2, 4096, 4096, 64, 5),
        gemv_desc(A2H, a2_W4, OUT34 + 4096, a2_b4, 4096, 4096, 64, 5),
        copy_desc(OUT12, OUT6 + 12288, 2048));
    // L6: nt_W1 (8 faces) + copy out3 -> OUT6 mid
    mg2(stream,
        gemv_desc(OUT34, nt_W1, NTH, nt_b1, 1024, 1024, 64, 0, 8, 1024, 1024),
        copy_desc(OUT34, OUT6 + 8192, 4096));
    // L7: nt_W2 -> out5 (relu-sparse; skips ~50% of L2-resident row reads)
    mg1(stream,
        gemv_desc(NTH, nt_W2, OUT6, nt_b2, 1024, 1024, 64, 5, 8, 1024, 1024));
    // L8: m2_W1 (470 MB, dense, nontemporal)
    mg1(stream, gemv_desc(OUT6, m2_W1, M2H, m2_b1, 14336, 8192, 448, 0,
                          1, 0, 0, nullptr, 0, 1));
    // L9: m2_W2 (268 MB, relu-sparse + nontemporal)
    mg1(stream, gemv_desc(M2H, m2_W2, HBUF, m2_b2, 8192, 8192, 256, 5,
                          1, 0, 0, nullptr, 0, 1));
    // L10: m3_W1 with inline maxpool over 8 faces
    mg1(stream, gemv_desc(HBUF, m3_W1, M3H1, m3_b1, 1024, 512, 16, 3));
    // L11: fused m3_W2 + head (40 blocks, redundant M3H2 per block)
    tail_kernel<<<40, TPB, 0, stream>>>(M3H1, m3_W2, m3_b2, m3_W3, m3_b3,
                                        (float*)d_out);
}